// Round 4
// baseline (7206.088 us; speedup 1.0000x reference)
//
#include <hip/hip_runtime.h>
#include <stdint.h>

typedef unsigned short u16;
typedef __attribute__((ext_vector_type(8))) short short8;
typedef __attribute__((ext_vector_type(4))) float fx4;

#define TB 512   // T
#define HD 512   // H
#define G3 1536  // 3*H

static __device__ __forceinline__ u16 f2bf(float f) {
  union { float f; uint32_t u; } v; v.f = f;
  return (u16)((v.u + 0x7fffu + ((v.u >> 16) & 1u)) >> 16);
}
static __device__ __forceinline__ float bf2f(u16 s) {
  union { uint32_t u; float f; } v; v.u = ((uint32_t)s) << 16;
  return v.f;
}
static __device__ __forceinline__ void gl_lds16(const void* g, void* l) {
  __builtin_amdgcn_global_load_lds(
      (const __attribute__((address_space(1))) uint32_t*)g,
      (__attribute__((address_space(3))) uint32_t*)l, 16, 0, 0);
}
static __device__ __forceinline__ float sigm(float x) { return 1.f / (1.f + __expf(-x)); }
static __device__ __forceinline__ float tanh_fast(float x) { return 1.f - 2.f / (__expf(2.f * x) + 1.f); }

// ---------------- prep: bf16 conversions + layouts ----------------
__global__ void prep_kernel(const float* Wx_f, const float* Wh_f, const float* Wx_b,
                            const float* Wh_b, const float* Wd,
                            u16* WxcT, u16* WhP, u16* WdT) {
  int tid = blockIdx.x * blockDim.x + threadIdx.x;
  int np = gridDim.x * blockDim.x;
  for (int i = tid; i < 3072 * 512; i += np) {
    int n = i >> 9, k = i & 511;
    float v = (n < G3) ? Wx_f[(size_t)k * G3 + n] : Wx_b[(size_t)k * G3 + (n - G3)];
    WxcT[i] = f2bf(v);
  }
  for (int i = tid; i < 2 * 96 * 16 * 512; i += np) {
    int jj = i & 7, lane = (i >> 3) & 63, kb = (i >> 9) & 15;
    int ntd = i >> 13;
    int nt = ntd % 96, d = ntd / 96;
    int n = nt * 16 + (lane & 15);
    int k = kb * 32 + (lane >> 4) * 8 + jj;
    const float* Wh = d ? Wh_b : Wh_f;
    WhP[i] = f2bf(Wh[(size_t)k * G3 + n]);
  }
  for (int i = tid; i < 512 * 1024; i += np) {
    int n = i >> 10, k = i & 1023;
    WdT[i] = f2bf(Wd[(size_t)k * 512 + n]);
  }
}

// ---------------- embedding gather-sum ----------------
__global__ void embed_kernel(const int* seqs, const float* emb, u16* embedded) {
  int r = blockIdx.x;
  int tid = threadIdx.x;
  const int* s = seqs + (size_t)r * 4;
  int c = tid * 4;
  float4 a = *(const float4*)(emb + (size_t)s[0] * HD + c);
  float4 b = *(const float4*)(emb + (size_t)s[1] * HD + c);
  float4 d = *(const float4*)(emb + (size_t)s[2] * HD + c);
  float4 e = *(const float4*)(emb + (size_t)s[3] * HD + c);
  float o0 = a.x + b.x + d.x + e.x;
  float o1 = a.y + b.y + d.y + e.y;
  float o2 = a.z + b.z + d.z + e.z;
  float o3 = a.w + b.w + d.w + e.w;
  uint2 uu;
  uu.x = (uint32_t)f2bf(o0) | ((uint32_t)f2bf(o1) << 16);
  uu.y = (uint32_t)f2bf(o2) | ((uint32_t)f2bf(o3) << 16);
  *(uint2*)(embedded + (size_t)r * HD + c) = uu;
}

// ---------------- gx = embedded @ [Wx_f | Wx_b] + b_in ----------------
__launch_bounds__(256)
__global__ void gemm_gx(const u16* A, const u16* Bt, const float* b_f, const float* b_b, u16* C) {
  __shared__ u16 As[128 * 32];
  __shared__ u16 Bs[128 * 32];
  int tn = blockIdx.x, tm = blockIdx.y;
  int tid = threadIdx.x, wv = tid >> 6, lane = tid & 63;
  int wm = wv >> 1, wn = wv & 1;
  int l15 = lane & 15, q = lane >> 4;
  fx4 acc[4][4];
  for (int i = 0; i < 4; i++) for (int jn = 0; jn < 4; jn++) acc[i][jn] = (fx4){0.f, 0.f, 0.f, 0.f};
  for (int kk = 0; kk < 16; kk++) {
    for (int cc = 0; cc < 2; cc++) {
      int row = wv * 32 + cc * 16 + (lane >> 2);
      int seg = lane & 3;
      gl_lds16(A + (size_t)(tm * 128 + row) * 512 + kk * 32 + seg * 8,
               (char*)As + (wv * 32 + cc * 16) * 64);
      gl_lds16(Bt + (size_t)(tn * 128 + row) * 512 + kk * 32 + seg * 8,
               (char*)Bs + (wv * 32 + cc * 16) * 64);
    }
    __builtin_amdgcn_s_waitcnt(0);
    __syncthreads();
    short8 af[4], bfr[4];
    for (int mt = 0; mt < 4; mt++)
      af[mt] = *(const short8*)((const char*)As + (wm * 64 + mt * 16 + l15) * 64 + q * 16);
    for (int nt = 0; nt < 4; nt++)
      bfr[nt] = *(const short8*)((const char*)Bs + (wn * 64 + nt * 16 + l15) * 64 + q * 16);
    for (int mt = 0; mt < 4; mt++)
      for (int nt = 0; nt < 4; nt++)
        acc[mt][nt] = __builtin_amdgcn_mfma_f32_16x16x32_bf16(af[mt], bfr[nt], acc[mt][nt], 0, 0, 0);
    __syncthreads();
  }
  for (int nt = 0; nt < 4; nt++) {
    int col = tn * 128 + wn * 64 + nt * 16 + l15;
    float bias = (col < G3) ? b_f[col] : b_b[col - G3];
    for (int mt = 0; mt < 4; mt++)
      for (int rg = 0; rg < 4; rg++) {
        int row = tm * 128 + wm * 64 + mt * 16 + q * 4 + rg;
        C[(size_t)row * 3072 + col] = f2bf(acc[mt][nt][rg] + bias);
      }
  }
}

// ---------------- persistent bidirectional GRU ----------------
// 16 WGs x 768 threads (12 waves). d = wg/8, isl = wg%8 owns 64 h-cols.
// wv 0-3 : K-lo MFMA + cell + publish(4 LLC stores) + per-quarter flag STORE.
// wv 4-7 : K-hi MFMA + red write; phase B: gather peer (wv-3) in parallel.
// wv 8-10: phase B: gx prefetch (dist 3) + gather peer (wv-3).
// wv 11  : phase B: gx prefetch + lag-1 coalesced out store from LDS stage.
// Cell waves' vmcnt chain = exactly the 4 hEx stores.
__launch_bounds__(768, 1)
__global__ void gru_kernel(const u16* gxAll, const u16* WhP, const float* b_f, const float* b_b,
                           u16* out_tmp, u16* hiddenA, uint32_t* hEx, int* flags) {
  __shared__ u16 hA[32 * 520];        // full h (bf16), row stride 520
  __shared__ float hOld[32 * 64];     // own slice, f32 master
  __shared__ float red[24 * 256];     // cross-wave K-half reduction
  __shared__ u16 gxs[4][32 * 192];    // quad-buffered gx slice [b][g][64]
  __shared__ u16 outStage[2][2048];   // lag-1 out staging [parity][b*64+c]
  int wgid = blockIdx.x;
  int d = wgid >> 3, isl = wgid & 7;
  int tid = threadIdx.x;
  int wv = tid >> 6, lane = tid & 63;
  int a = wv & 3;           // quarter (wv<8)
  int jh = (wv >> 2) & 1;   // K half (wv<8)
  int l15 = lane & 15, q = lane >> 4;

  for (int i = tid; i < 32 * 520 / 2; i += 768) ((uint32_t*)hA)[i] = 0u;
  for (int i = tid; i < 2048; i += 768) hOld[i] = 0.f;

  short8 Bf[3][8];
  if (wv < 8) {
    for (int g = 0; g < 3; g++) {
      int ntg = g * 32 + isl * 4 + a;
      for (int kk = 0; kk < 8; kk++) {
        int kb = jh * 8 + kk;
        Bf[g][kk] = *(const short8*)(WhP + ((((size_t)d * 96 + ntg) * 16 + kb) * 64 + lane) * 8);
      }
    }
  }
  const float* bias = d ? b_b : b_f;
  int cloc = a * 16 + l15;
  int gc = isl * 64 + cloc;
  float brz = bias[G3 + gc];
  float brr = bias[G3 + 512 + gc];
  float brn = bias[G3 + 1024 + gc];

  // prologue: stage gx for steps 0,1,2 into buffers 0,1,2 (one chunk per wave)
  for (int pb = 0; pb < 3; pb++) {
    int tp = d ? (TB - 1 - pb) : pb;
    int it = wv;  // 12 waves x 12 chunks
    int slot = it * 64 + lane;
    int chunk = slot >> 3, sub = slot & 7;
    int b = chunk / 3, g = chunk - b * 3;
    gl_lds16(gxAll + (size_t)(b * TB + tp) * 3072 + d * 1536 + g * 512 + isl * 64 + sub * 8,
             (char*)gxs[pb] + it * 1024);
  }
  __builtin_amdgcn_s_waitcnt(0);
  __syncthreads();

  for (int s = 0; s < TB; s++) {
    int t = d ? (TB - 1 - s) : s;
    // ---- phase A: MFMA + cross-K partials (wv<8); others idle ----
    fx4 acc[2][3];
    if (wv < 8) {
      for (int mt = 0; mt < 2; mt++) for (int g = 0; g < 3; g++) acc[mt][g] = (fx4){0.f, 0.f, 0.f, 0.f};
      for (int mt = 0; mt < 2; mt++) {
        short8 Af[8];
        for (int kk = 0; kk < 8; kk++) {
          int kb = jh * 8 + kk;
          Af[kk] = *(const short8*)((const char*)hA + (mt * 16 + l15) * 1040 + kb * 64 + q * 16);
        }
        for (int g = 0; g < 3; g++)
          for (int kk = 0; kk < 8; kk++)
            acc[mt][g] = __builtin_amdgcn_mfma_f32_16x16x32_bf16(Af[kk], Bf[g][kk], acc[mt][g], 0, 0, 0);
      }
      if (jh == 1) {
        for (int mt = 0; mt < 2; mt++)
          for (int g = 0; g < 3; g++) {
            float* tp = red + ((a * 2 + mt) * 3 + g) * 256;
            for (int rg = 0; rg < 4; rg++) tp[(q * 4 + rg) * 16 + l15] = acc[mt][g][rg];
          }
      }
    }
    __syncthreads();  // barrier 1 (no outstanding VMEM on anyone)

    // ---- phase B ----
    if (wv >= 8 && s + 3 < TB) {  // distance-3 gx prefetch (drains in poll slack)
      int t3 = d ? (TB - 4 - s) : (s + 3);
      char* dst = (char*)gxs[(s + 3) & 3];
      for (int it = (wv - 8) * 3; it < (wv - 8) * 3 + 3; it++) {
        int slot = it * 64 + lane;
        int chunk = slot >> 3, sub = slot & 7;
        int b = chunk / 3, g = chunk - b * 3;
        gl_lds16(gxAll + (size_t)(b * TB + t3) * 3072 + d * 1536 + g * 512 + isl * 64 + sub * 8,
                 dst + it * 1024);
      }
    }
    if (wv < 4) {  // cell + publish + flag
      const u16* gxc = gxs[s & 3];
      u16 hv[2][4];
      for (int mt = 0; mt < 2; mt++) {
        const float* tpz = red + ((a * 2 + mt) * 3 + 0) * 256;
        const float* tpr = red + ((a * 2 + mt) * 3 + 1) * 256;
        const float* tpn = red + ((a * 2 + mt) * 3 + 2) * 256;
        for (int rg = 0; rg < 4; rg++) {
          int b = mt * 16 + q * 4 + rg;
          int fi = (q * 4 + rg) * 16 + l15;
          float ghz = acc[mt][0][rg] + tpz[fi] + brz;
          float ghr = acc[mt][1][rg] + tpr[fi] + brr;
          float ghn = acc[mt][2][rg] + tpn[fi] + brn;
          float gxz = bf2f(gxc[b * 192 + cloc]);
          float gxr = bf2f(gxc[b * 192 + 64 + cloc]);
          float gxn = bf2f(gxc[b * 192 + 128 + cloc]);
          float z = sigm(gxz + ghz);
          float rr = sigm(gxr + ghr);
          float hc = tanh_fast(gxn + rr * ghn);
          float hp = hOld[b * 64 + cloc];
          float hnw = z * hp + (1.f - z) * hc;
          hOld[b * 64 + cloc] = hnw;
          u16 hb = f2bf(hnw);
          hv[mt][rg] = hb;
          hA[b * 520 + gc] = hb;
          outStage[s & 1][b * 64 + cloc] = hb;
        }
      }
      if (s < TB - 1) {
        int p = (s + 1) & 1;
        uint32_t* slot = hEx + ((size_t)(d * 2 + p) * 8 + isl) * 1024;
        for (int mt = 0; mt < 2; mt++)
          for (int pr = 0; pr < 2; pr++) {
            uint32_t pk = (uint32_t)hv[mt][2 * pr] | ((uint32_t)hv[mt][2 * pr + 1] << 16);
            __hip_atomic_store(&slot[cloc * 16 + mt * 8 + q * 2 + pr], pk,
                               __ATOMIC_RELAXED, __HIP_MEMORY_SCOPE_AGENT);
          }
        __builtin_amdgcn_s_waitcnt(0);  // drains exactly the 4 hEx stores
        if (lane == 0)
          __hip_atomic_store(&flags[wgid * 16 + a], s + 1,
                             __ATOMIC_RELAXED, __HIP_MEMORY_SCOPE_AGENT);
      } else {  // final step: hidden state out
        for (int mt = 0; mt < 2; mt++)
          for (int rg = 0; rg < 4; rg++)
            hiddenA[(size_t)(mt * 16 + q * 4 + rg) * 1024 + d * 512 + gc] = hv[mt][rg];
      }
    } else if (wv < 11) {  // wv 4..10: poll + gather one peer (parallel)
      if (s < TB - 1) {
        int pj = (isl + (wv - 3)) & 7;
        int peer = d * 8 + pj;
        int target = s + 1;
        const int* pf = flags + peer * 16;
        long long spins = 0;
        while (true) {
          int f0 = __hip_atomic_load(pf + 0, __ATOMIC_RELAXED, __HIP_MEMORY_SCOPE_AGENT);
          int f1 = __hip_atomic_load(pf + 1, __ATOMIC_RELAXED, __HIP_MEMORY_SCOPE_AGENT);
          int f2 = __hip_atomic_load(pf + 2, __ATOMIC_RELAXED, __HIP_MEMORY_SCOPE_AGENT);
          int f3 = __hip_atomic_load(pf + 3, __ATOMIC_RELAXED, __HIP_MEMORY_SCOPE_AGENT);
          int m = min(min(f0, f1), min(f2, f3));
          if (m >= target || ++spins > (1LL << 38)) break;
        }
        const uint32_t* src = hEx + ((size_t)(d * 2 + ((s + 1) & 1)) * 8 + pj) * 1024 + lane * 16;
        uint32_t v[16];
        for (int k = 0; k < 16; k++)
          v[k] = __hip_atomic_load(&src[k], __ATOMIC_RELAXED, __HIP_MEMORY_SCOPE_AGENT);
        for (int k = 0; k < 16; k++) {
          int mt = k >> 3, rem = k & 7;
          int row0 = mt * 16 + (rem >> 1) * 4 + (rem & 1) * 2;
          hA[row0 * 520 + pj * 64 + lane] = (u16)(v[k] & 0xffffu);
          hA[(row0 + 1) * 520 + pj * 64 + lane] = (u16)(v[k] >> 16);
        }
      }
    } else {  // wv == 11: lag-1 coalesced out store
      if (s >= 1) {
        int tprev = d ? (TB - s) : (s - 1);
        uint32_t* op = (uint32_t*)(out_tmp + ((size_t)(d * 8 + isl) * 512 + tprev) * 2048);
        const uint32_t* st = (const uint32_t*)outStage[(s - 1) & 1];
        for (int k = 0; k < 16; k++) op[lane + 64 * k] = st[lane + 64 * k];
      }
    }
    __syncthreads();  // barrier 2
  }
  // epilogue: store the last step's outputs
  if (wv == 11) {
    int tlast = d ? 0 : (TB - 1);
    uint32_t* op = (uint32_t*)(out_tmp + ((size_t)(d * 8 + isl) * 512 + tlast) * 2048);
    const uint32_t* st = (const uint32_t*)outStage[(TB - 1) & 1];
    for (int k = 0; k < 16; k++) op[lane + 64 * k] = st[lane + 64 * k];
  }
}

// ---------------- projection: [out_f|out_b] @ Wd + bd ----------------
// A rows (tm<128) come from permuted out_tmp[d][isl][t][b][64].
__launch_bounds__(256)
__global__ void gemm_proj(const u16* Aall, const u16* hiddenA, const u16* WdT,
                          const float* bd, float* out) {
  __shared__ u16 As[128 * 32];
  __shared__ u16 Bs[128 * 32];
  int tn = blockIdx.x, tm = blockIdx.y;
  int b0 = tm >> 2, tbase = (tm & 3) * 128;
  int tid = threadIdx.x, wv = tid >> 6, lane = tid & 63;
  int wm = wv >> 1, wn = wv & 1;
  int l15 = lane & 15, q = lane >> 4;
  fx4 acc[4][4];
  for (int i = 0; i < 4; i++) for (int jn = 0; jn < 4; jn++) acc[i][jn] = (fx4){0.f, 0.f, 0.f, 0.f};
  for (int kk = 0; kk < 32; kk++) {
    for (int cc = 0; cc < 2; cc++) {
      int row = wv * 32 + cc * 16 + (lane >> 2);
      int seg = lane & 3;
      int k = kk * 32 + seg * 8;
      const u16* ap;
      if (tm < 128) {
        int d2 = k >> 9, isl2 = (k >> 6) & 7, c = k & 63;
        ap = Aall + ((size_t)((d2 * 8 + isl2) * 512) + tbase + row) * 2048 + b0 * 64 + c;
      } else {
        ap = hiddenA + (size_t)row * 1024 + k;
      }
      gl_lds16(ap, (char*)As + (wv * 32 + cc * 16) * 64);
      gl_lds16(WdT + (size_t)(tn * 128 + row) * 1024 + k,
               (char*)Bs + (wv * 32 + cc * 16) * 64);
    }
    __builtin_amdgcn_s_waitcnt(0);
    __syncthreads();
    short8 af[4], bfr[4];
    for (int mt = 0; mt < 4; mt++)
      af[mt] = *(const short8*)((const char*)As + (wm * 64 + mt * 16 + l15) * 64 + q * 16);
    for (int nt = 0; nt < 4; nt++)
      bfr[nt] = *(const short8*)((const char*)Bs + (wn * 64 + nt * 16 + l15) * 64 + q * 16);
    for (int mt = 0; mt < 4; mt++)
      for (int nt = 0; nt < 4; nt++)
        acc[mt][nt] = __builtin_amdgcn_mfma_f32_16x16x32_bf16(af[mt], bfr[nt], acc[mt][nt], 0, 0, 0);
    __syncthreads();
  }
  for (int nt = 0; nt < 4; nt++) {
    int col = tn * 128 + wn * 64 + nt * 16 + l15;
    float bias = bd[col];
    for (int mt = 0; mt < 4; mt++)
      for (int rg = 0; rg < 4; rg++) {
        int row = wm * 64 + mt * 16 + q * 4 + rg;
        float v = acc[mt][nt][rg] + bias;
        if (tm < 128) out[((size_t)tm * 128 + row) * 512 + col] = v;
        else if (row < 32) out[(size_t)16384 * 512 + (size_t)row * 512 + col] = v;
      }
  }
}

extern "C" void kernel_launch(void* const* d_in, const int* in_sizes, int n_in,
                              void* d_out, int out_size, void* d_ws, size_t ws_size,
                              hipStream_t stream) {
  (void)in_sizes; (void)n_in; (void)out_size; (void)ws_size;
  const int* seqs = (const int*)d_in[0];
  const float* emb = (const float*)d_in[2];
  const float* Wx_f = (const float*)d_in[3];
  const float* Wh_f = (const float*)d_in[4];
  const float* b_f = (const float*)d_in[5];
  const float* Wx_b = (const float*)d_in[6];
  const float* Wh_b = (const float*)d_in[7];
  const float* b_b = (const float*)d_in[8];
  const float* Wd = (const float*)d_in[9];
  const float* bd = (const float*)d_in[10];
  char* ws = (char*)d_ws;
  u16* WxcT     = (u16*)(ws + 0);
  u16* WhP      = (u16*)(ws + 3145728);
  u16* WdT      = (u16*)(ws + 6291456);
  u16* embedded = (u16*)(ws + 7340032);
  u16* gxAll    = (u16*)(ws + 24117248);
  u16* out_tmp  = (u16*)(ws + 124780544);
  u16* hiddenA  = (u16*)(ws + 158334976);
  uint32_t* hEx = (uint32_t*)(ws + 158597120);
  int* flags    = (int*)(ws + 158728192);  // 16 WGs x 16 words (64B lines)

  hipMemsetAsync(flags, 0, 16 * 16 * sizeof(int), stream);
  prep_kernel<<<512, 256, 0, stream>>>(Wx_f, Wh_f, Wx_b, Wh_b, Wd, WxcT, WhP, WdT);
  embed_kernel<<<16384, 128, 0, stream>>>(seqs, emb, embedded);
  gemm_gx<<<dim3(24, 128), 256, 0, stream>>>(embedded, WxcT, b_f, b_b, gxAll);
  gru_kernel<<<16, 768, 0, stream>>>(gxAll, WhP, b_f, b_b, out_tmp, hiddenA, hEx, flags);
  gemm_proj<<<dim3(4, 129), 256, 0, stream>>>(out_tmp, hiddenA, WdT, bd, (float*)d_out);
}

// Round 5
// 2988.421 us; speedup vs baseline: 2.4113x; 2.4113x over previous
//
#include <hip/hip_runtime.h>
#include <stdint.h>

typedef unsigned short u16;
typedef __attribute__((ext_vector_type(8))) short short8;
typedef __attribute__((ext_vector_type(4))) float fx4;

#define TB 512   // T
#define HD 512   // H
#define G3 1536  // 3*H
#define HAS 536  // hA row stride in u16 (1072 B: 16B-aligned, bank stride 12 -> ~4-way)

static __device__ __forceinline__ u16 f2bf(float f) {
  union { float f; uint32_t u; } v; v.f = f;
  return (u16)((v.u + 0x7fffu + ((v.u >> 16) & 1u)) >> 16);
}
static __device__ __forceinline__ float bf2f(u16 s) {
  union { uint32_t u; float f; } v; v.u = ((uint32_t)s) << 16;
  return v.f;
}
static __device__ __forceinline__ void gl_lds16(const void* g, void* l) {
  __builtin_amdgcn_global_load_lds(
      (const __attribute__((address_space(1))) uint32_t*)g,
      (__attribute__((address_space(3))) uint32_t*)l, 16, 0, 0);
}
static __device__ __forceinline__ float sigm(float x) { return 1.f / (1.f + __expf(-x)); }
static __device__ __forceinline__ float tanh_fast(float x) { return 1.f - 2.f / (__expf(2.f * x) + 1.f); }

// ---------------- prep: bf16 conversions + layouts ----------------
__global__ void prep_kernel(const float* Wx_f, const float* Wh_f, const float* Wx_b,
                            const float* Wh_b, const float* Wd,
                            u16* WxcT, u16* WhP, u16* WdT) {
  int tid = blockIdx.x * blockDim.x + threadIdx.x;
  int np = gridDim.x * blockDim.x;
  for (int i = tid; i < 3072 * 512; i += np) {
    int n = i >> 9, k = i & 511;
    float v = (n < G3) ? Wx_f[(size_t)k * G3 + n] : Wx_b[(size_t)k * G3 + (n - G3)];
    WxcT[i] = f2bf(v);
  }
  for (int i = tid; i < 2 * 96 * 16 * 512; i += np) {
    int jj = i & 7, lane = (i >> 3) & 63, kb = (i >> 9) & 15;
    int ntd = i >> 13;
    int nt = ntd % 96, d = ntd / 96;
    int n = nt * 16 + (lane & 15);
    int k = kb * 32 + (lane >> 4) * 8 + jj;
    const float* Wh = d ? Wh_b : Wh_f;
    WhP[i] = f2bf(Wh[(size_t)k * G3 + n]);
  }
  for (int i = tid; i < 512 * 1024; i += np) {
    int n = i >> 10, k = i & 1023;
    WdT[i] = f2bf(Wd[(size_t)k * 512 + n]);
  }
}

// ---------------- embedding gather-sum ----------------
__global__ void embed_kernel(const int* seqs, const float* emb, u16* embedded) {
  int r = blockIdx.x;
  int tid = threadIdx.x;
  const int* s = seqs + (size_t)r * 4;
  int c = tid * 4;
  float4 a = *(const float4*)(emb + (size_t)s[0] * HD + c);
  float4 b = *(const float4*)(emb + (size_t)s[1] * HD + c);
  float4 d = *(const float4*)(emb + (size_t)s[2] * HD + c);
  float4 e = *(const float4*)(emb + (size_t)s[3] * HD + c);
  float o0 = a.x + b.x + d.x + e.x;
  float o1 = a.y + b.y + d.y + e.y;
  float o2 = a.z + b.z + d.z + e.z;
  float o3 = a.w + b.w + d.w + e.w;
  uint2 uu;
  uu.x = (uint32_t)f2bf(o0) | ((uint32_t)f2bf(o1) << 16);
  uu.y = (uint32_t)f2bf(o2) | ((uint32_t)f2bf(o3) << 16);
  *(uint2*)(embedded + (size_t)r * HD + c) = uu;
}

// ---------------- gx = embedded @ [Wx_f | Wx_b] + b_in ----------------
__launch_bounds__(256)
__global__ void gemm_gx(const u16* A, const u16* Bt, const float* b_f, const float* b_b, u16* C) {
  __shared__ u16 As[128 * 32];
  __shared__ u16 Bs[128 * 32];
  int tn = blockIdx.x, tm = blockIdx.y;
  int tid = threadIdx.x, wv = tid >> 6, lane = tid & 63;
  int wm = wv >> 1, wn = wv & 1;
  int l15 = lane & 15, q = lane >> 4;
  fx4 acc[4][4];
  for (int i = 0; i < 4; i++) for (int jn = 0; jn < 4; jn++) acc[i][jn] = (fx4){0.f, 0.f, 0.f, 0.f};
  for (int kk = 0; kk < 16; kk++) {
    for (int cc = 0; cc < 2; cc++) {
      int row = wv * 32 + cc * 16 + (lane >> 2);
      int seg = lane & 3;
      gl_lds16(A + (size_t)(tm * 128 + row) * 512 + kk * 32 + seg * 8,
               (char*)As + (wv * 32 + cc * 16) * 64);
      gl_lds16(Bt + (size_t)(tn * 128 + row) * 512 + kk * 32 + seg * 8,
               (char*)Bs + (wv * 32 + cc * 16) * 64);
    }
    __builtin_amdgcn_s_waitcnt(0);
    __syncthreads();
    short8 af[4], bfr[4];
    for (int mt = 0; mt < 4; mt++)
      af[mt] = *(const short8*)((const char*)As + (wm * 64 + mt * 16 + l15) * 64 + q * 16);
    for (int nt = 0; nt < 4; nt++)
      bfr[nt] = *(const short8*)((const char*)Bs + (wn * 64 + nt * 16 + l15) * 64 + q * 16);
    for (int mt = 0; mt < 4; mt++)
      for (int nt = 0; nt < 4; nt++)
        acc[mt][nt] = __builtin_amdgcn_mfma_f32_16x16x32_bf16(af[mt], bfr[nt], acc[mt][nt], 0, 0, 0);
    __syncthreads();
  }
  for (int nt = 0; nt < 4; nt++) {
    int col = tn * 128 + wn * 64 + nt * 16 + l15;
    float bias = (col < G3) ? b_f[col] : b_b[col - G3];
    for (int mt = 0; mt < 4; mt++)
      for (int rg = 0; rg < 4; rg++) {
        int row = tm * 128 + wm * 64 + mt * 16 + q * 4 + rg;
        C[(size_t)row * 3072 + col] = f2bf(acc[mt][nt][rg] + bias);
      }
  }
}

// ---------------- persistent bidirectional GRU ----------------
// 16 WGs x 512 threads. d = wg/8, isl = wg%8 owns h-cols [isl*64, isl*64+64).
// Exchange protocol: tagged 8B atomics. Each unit = (tag=s+1)<<32 | dword of
// 2 bf16 (row r, cols 2cp,2cp+1). Publishers fire-and-forget 4 units/lane
// (no drain, no flag). Pollers poll the DATA units directly with s_sleep
// backoff; tag match == data valid (8B store is atomic at MALL).
// Overwrite safety: writer at step s+2 requires all peers' step-s+1 publish,
// which requires their step-s gather complete -> 2-slot parity suffices.
__launch_bounds__(512, 2)
__global__ void gru_kernel(const u16* gxAll, const u16* WhP, const float* b_f, const float* b_b,
                           u16* out_tmp, u16* hiddenA, uint64_t* hEx64) {
  __shared__ u16 hA[32 * HAS];       // full h (bf16), row stride HAS
  __shared__ float hOld[32 * 64];    // own slice, f32 master
  __shared__ float red[24 * 256];    // cross-wave K-half reduction
  __shared__ u16 gxs[3][32 * 192];   // triple-buffered gx slice [b][g][64]
  int wgid = blockIdx.x;
  int d = wgid >> 3, isl = wgid & 7;
  int tid = threadIdx.x;
  int wv = tid >> 6, lane = tid & 63;
  int a = wv & 3;      // n-tile quarter (16 h-cols)
  int jh = wv >> 2;    // K half
  int l15 = lane & 15, q = lane >> 4;

  for (int i = tid; i < 32 * HAS / 2; i += 512) ((uint32_t*)hA)[i] = 0u;
  for (int i = tid; i < 2048; i += 512) hOld[i] = 0.f;

  short8 Bf[3][8];
  for (int g = 0; g < 3; g++) {
    int ntg = g * 32 + isl * 4 + a;
    for (int kk = 0; kk < 8; kk++) {
      int kb = jh * 8 + kk;
      Bf[g][kk] = *(const short8*)(WhP + ((((size_t)d * 96 + ntg) * 16 + kb) * 64 + lane) * 8);
    }
  }
  const float* bias = d ? b_b : b_f;
  int cloc = a * 16 + l15;
  int gc = isl * 64 + cloc;
  int cp = a * 8 + (l15 >> 1);   // col-pair index within own 64-slice
  int oddl = l15 & 1;
  float brz = bias[G3 + gc];
  float brr = bias[G3 + 512 + gc];
  float brn = bias[G3 + 1024 + gc];

  // prologue: stage gx for steps 0,1 into buffers 0,1
  for (int pb = 0; pb < 2; pb++) {
    int tp = d ? (TB - 1 - pb) : pb;
    for (int it = wv; it < 12; it += 8) {
      int slot = it * 64 + lane;
      int chunk = slot >> 3, sub = slot & 7;
      int b = chunk / 3, g = chunk - b * 3;
      gl_lds16(gxAll + (size_t)(b * TB + tp) * 3072 + d * 1536 + g * 512 + isl * 64 + sub * 8,
               (char*)gxs[pb] + it * 1024);
    }
  }
  __builtin_amdgcn_s_waitcnt(0);
  __syncthreads();

  for (int s = 0; s < TB; s++) {
    int t = d ? (TB - 1 - s) : s;
    // ---- phase A: (gather waves) dist-2 gx prefetch; all: MFMA + partials ----
    if (jh == 1 && s + 2 < TB) {
      int t2 = d ? (TB - 3 - s) : (s + 2);
      char* dst = (char*)gxs[(s + 2) % 3];
      for (int it = a * 3; it < a * 3 + 3; it++) {
        int slot = it * 64 + lane;
        int chunk = slot >> 3, sub = slot & 7;
        int b = chunk / 3, g = chunk - b * 3;
        gl_lds16(gxAll + (size_t)(b * TB + t2) * 3072 + d * 1536 + g * 512 + isl * 64 + sub * 8,
                 dst + it * 1024);
      }
    }
    fx4 acc[2][3];
    for (int mt = 0; mt < 2; mt++) for (int g = 0; g < 3; g++) acc[mt][g] = (fx4){0.f, 0.f, 0.f, 0.f};
    for (int mt = 0; mt < 2; mt++) {
      short8 Af[8];
      for (int kk = 0; kk < 8; kk++) {
        int kb = jh * 8 + kk;
        Af[kk] = *(const short8*)((const char*)hA + (mt * 16 + l15) * (HAS * 2) + kb * 64 + q * 16);
      }
      for (int g = 0; g < 3; g++)
        for (int kk = 0; kk < 8; kk++)
          acc[mt][g] = __builtin_amdgcn_mfma_f32_16x16x32_bf16(Af[kk], Bf[g][kk], acc[mt][g], 0, 0, 0);
    }
    if (jh == 1) {
      for (int mt = 0; mt < 2; mt++)
        for (int g = 0; g < 3; g++) {
          float* tp = red + ((a * 2 + mt) * 3 + g) * 256;
          for (int rg = 0; rg < 4; rg++) tp[(q * 4 + rg) * 16 + l15] = acc[mt][g][rg];
        }
    }
    __syncthreads();  // barrier 1

    // ---- phase B ----
    if (jh == 0) {  // cell + pack + publish (fire-and-forget) + out store
      const u16* gxc = gxs[s % 3];
      u16 hv[2][4];
      for (int mt = 0; mt < 2; mt++) {
        const float* tpz = red + ((a * 2 + mt) * 3 + 0) * 256;
        const float* tpr = red + ((a * 2 + mt) * 3 + 1) * 256;
        const float* tpn = red + ((a * 2 + mt) * 3 + 2) * 256;
        for (int rg = 0; rg < 4; rg++) {
          int b = mt * 16 + q * 4 + rg;
          int fi = (q * 4 + rg) * 16 + l15;
          float ghz = acc[mt][0][rg] + tpz[fi] + brz;
          float ghr = acc[mt][1][rg] + tpr[fi] + brr;
          float ghn = acc[mt][2][rg] + tpn[fi] + brn;
          float gxz = bf2f(gxc[b * 192 + cloc]);
          float gxr = bf2f(gxc[b * 192 + 64 + cloc]);
          float gxn = bf2f(gxc[b * 192 + 128 + cloc]);
          float z = sigm(gxz + ghz);
          float rr = sigm(gxr + ghr);
          float hc = tanh_fast(gxn + rr * ghn);
          float hp = hOld[b * 64 + cloc];
          float hnw = z * hp + (1.f - z) * hc;
          hOld[b * 64 + cloc] = hnw;
          hv[mt][rg] = f2bf(hnw);
        }
      }
      // pack col-pairs via partner shuffle: dword = (col 2cp) | (col 2cp+1)<<16
      uint32_t dw[2][2];  // [mt][rgsel]; even lane handles rg 0,1; odd rg 2,3
      for (int mt = 0; mt < 2; mt++)
        for (int rg = 0; rg < 4; rg++) {
          uint32_t own = hv[mt][rg];
          uint32_t part = (uint32_t)__shfl_xor((int)own, 1);
          uint32_t v = oddl ? (part | (own << 16)) : (own | (part << 16));
          if ((rg >> 1) == oddl) dw[mt][rg & 1] = v;
        }
      // own slice into hA (dword writes) + publish + out store
      uint64_t* slot = hEx64 + ((size_t)(d * 2 + ((s + 1) & 1)) * 8 + isl) * 1024;
      uint32_t* outp = (uint32_t*)(out_tmp + ((size_t)(d * 8 + isl) * 512 + t) * 2048);
      uint64_t tagw = ((uint64_t)(uint32_t)(s + 1)) << 32;
      for (int mt = 0; mt < 2; mt++)
        for (int rgsel = 0; rgsel < 2; rgsel++) {
          int r = mt * 16 + q * 4 + oddl * 2 + rgsel;
          uint32_t v = dw[mt][rgsel];
          *(uint32_t*)((char*)hA + r * (HAS * 2) + isl * 128 + cp * 4) = v;
          if (s < TB - 1)
            __hip_atomic_store(&slot[r * 32 + cp], tagw | v,
                               __ATOMIC_RELAXED, __HIP_MEMORY_SCOPE_AGENT);
          outp[r * 32 + cp] = v;
        }
      if (s == TB - 1)
        for (int mt = 0; mt < 2; mt++)
          for (int rg = 0; rg < 4; rg++)
            hiddenA[(size_t)(mt * 16 + q * 4 + rg) * 1024 + d * 512 + gc] = hv[mt][rg];
    } else if (s < TB - 1) {  // gather waves: poll-on-data, 2 peers
      uint32_t tag = (uint32_t)(s + 1);
      for (int pi = 0; pi < 2; pi++) {
        int po = (wv - 3) + pi * 4;  // wv4:{1,5} wv5:{2,6} wv6:{3,7} wv7:{4}
        if (po > 7) break;
        int pj = (isl + po) & 7;
        const uint64_t* src = hEx64 + ((size_t)(d * 2 + ((s + 1) & 1)) * 8 + pj) * 1024 + lane;
        uint64_t v[16];
        for (int k = 0; k < 16; k++)
          v[k] = __hip_atomic_load(&src[64 * k], __ATOMIC_RELAXED, __HIP_MEMORY_SCOPE_AGENT);
        long long spins = 0;
        while (true) {
          uint32_t bad = 0;
          for (int k = 0; k < 16; k++) bad |= ((uint32_t)(v[k] >> 32)) ^ tag;
          unsigned long long anybad = __ballot(bad != 0);
          if (!anybad || ++spins > (1LL << 28)) break;
          __builtin_amdgcn_s_sleep(1);
          for (int k = 0; k < 16; k++)
            if ((uint32_t)(v[k] >> 32) != tag)
              v[k] = __hip_atomic_load(&src[64 * k], __ATOMIC_RELAXED, __HIP_MEMORY_SCOPE_AGENT);
        }
        for (int k = 0; k < 16; k++) {
          int u = lane + 64 * k;
          int r = u >> 5, cpp = u & 31;
          *(uint32_t*)((char*)hA + r * (HAS * 2) + pj * 128 + cpp * 4) = (uint32_t)v[k];
        }
      }
    }
    __syncthreads();  // barrier 2
  }
}

// ---------------- projection: [out_f|out_b] @ Wd + bd ----------------
// A rows (tm<128) come from permuted out_tmp[d][isl][t][b][64].
__launch_bounds__(256)
__global__ void gemm_proj(const u16* Aall, const u16* hiddenA, const u16* WdT,
                          const float* bd, float* out) {
  __shared__ u16 As[128 * 32];
  __shared__ u16 Bs[128 * 32];
  int tn = blockIdx.x, tm = blockIdx.y;
  int b0 = tm >> 2, tbase = (tm & 3) * 128;
  int tid = threadIdx.x, wv = tid >> 6, lane = tid & 63;
  int wm = wv >> 1, wn = wv & 1;
  int l15 = lane & 15, q = lane >> 4;
  fx4 acc[4][4];
  for (int i = 0; i < 4; i++) for (int jn = 0; jn < 4; jn++) acc[i][jn] = (fx4){0.f, 0.f, 0.f, 0.f};
  for (int kk = 0; kk < 32; kk++) {
    for (int cc = 0; cc < 2; cc++) {
      int row = wv * 32 + cc * 16 + (lane >> 2);
      int seg = lane & 3;
      int k = kk * 32 + seg * 8;
      const u16* ap;
      if (tm < 128) {
        int d2 = k >> 9, isl2 = (k >> 6) & 7, c = k & 63;
        ap = Aall + ((size_t)((d2 * 8 + isl2) * 512) + tbase + row) * 2048 + b0 * 64 + c;
      } else {
        ap = hiddenA + (size_t)row * 1024 + k;
      }
      gl_lds16(ap, (char*)As + (wv * 32 + cc * 16) * 64);
      gl_lds16(WdT + (size_t)(tn * 128 + row) * 1024 + k,
               (char*)Bs + (wv * 32 + cc * 16) * 64);
    }
    __builtin_amdgcn_s_waitcnt(0);
    __syncthreads();
    short8 af[4], bfr[4];
    for (int mt = 0; mt < 4; mt++)
      af[mt] = *(const short8*)((const char*)As + (wm * 64 + mt * 16 + l15) * 64 + q * 16);
    for (int nt = 0; nt < 4; nt++)
      bfr[nt] = *(const short8*)((const char*)Bs + (wn * 64 + nt * 16 + l15) * 64 + q * 16);
    for (int mt = 0; mt < 4; mt++)
      for (int nt = 0; nt < 4; nt++)
        acc[mt][nt] = __builtin_amdgcn_mfma_f32_16x16x32_bf16(af[mt], bfr[nt], acc[mt][nt], 0, 0, 0);
    __syncthreads();
  }
  for (int nt = 0; nt < 4; nt++) {
    int col = tn * 128 + wn * 64 + nt * 16 + l15;
    float bias = bd[col];
    for (int mt = 0; mt < 4; mt++)
      for (int rg = 0; rg < 4; rg++) {
        int row = wm * 64 + mt * 16 + q * 4 + rg;
        float v = acc[mt][nt][rg] + bias;
        if (tm < 128) out[((size_t)tm * 128 + row) * 512 + col] = v;
        else if (row < 32) out[(size_t)16384 * 512 + (size_t)row * 512 + col] = v;
      }
  }
}

extern "C" void kernel_launch(void* const* d_in, const int* in_sizes, int n_in,
                              void* d_out, int out_size, void* d_ws, size_t ws_size,
                              hipStream_t stream) {
  (void)in_sizes; (void)n_in; (void)out_size; (void)ws_size;
  const int* seqs = (const int*)d_in[0];
  const float* emb = (const float*)d_in[2];
  const float* Wx_f = (const float*)d_in[3];
  const float* Wh_f = (const float*)d_in[4];
  const float* b_f = (const float*)d_in[5];
  const float* Wx_b = (const float*)d_in[6];
  const float* Wh_b = (const float*)d_in[7];
  const float* b_b = (const float*)d_in[8];
  const float* Wd = (const float*)d_in[9];
  const float* bd = (const float*)d_in[10];
  char* ws = (char*)d_ws;
  u16* WxcT      = (u16*)(ws + 0);
  u16* WhP       = (u16*)(ws + 3145728);
  u16* WdT       = (u16*)(ws + 6291456);
  u16* embedded  = (u16*)(ws + 7340032);
  u16* gxAll     = (u16*)(ws + 24117248);
  u16* out_tmp   = (u16*)(ws + 124780544);
  u16* hiddenA   = (u16*)(ws + 158334976);   // 64 KB used
  uint64_t* hEx64 = (uint64_t*)(ws + 158400512);  // 2d x 2par x 8isl x 8KB = 256 KB

  prep_kernel<<<512, 256, 0, stream>>>(Wx_f, Wh_f, Wx_b, Wh_b, Wd, WxcT, WhP, WdT);
  embed_kernel<<<16384, 128, 0, stream>>>(seqs, emb, embedded);
  gemm_gx<<<dim3(24, 128), 256, 0, stream>>>(embedded, WxcT, b_f, b_b, gxAll);
  gru_kernel<<<16, 512, 0, stream>>>(gxAll, WhP, b_f, b_b, out_tmp, hiddenA, hEx64);
  gemm_proj<<<dim3(4, 129), 256, 0, stream>>>(out_tmp, hiddenA, WdT, bd, (float*)d_out);
}